// Round 5
// baseline (609.350 us; speedup 1.0000x reference)
//
#include <hip/hip_runtime.h>

#define T_  8192
#define E_  256
#define BS_ 128

typedef __attribute__((ext_vector_type(8))) short bf16x8;
typedef __attribute__((ext_vector_type(4))) float f32x4;
typedef __attribute__((ext_vector_type(4))) unsigned int u32x4;

// Pair-convert via native __bf16 casts -> v_cvt_pk_bf16_f32 (RTNE).
__device__ __forceinline__ unsigned pkbf(float a, float b) {
    unsigned short ua = __builtin_bit_cast(unsigned short, (__bf16)a);
    unsigned short ub = __builtin_bit_cast(unsigned short, (__bf16)b);
    return (unsigned)ua | ((unsigned)ub << 16);
}

__device__ __forceinline__ unsigned short bf1(float a) {
    return __builtin_bit_cast(unsigned short, (__bf16)a);
}

__device__ __forceinline__ bf16x8 pack8(f32x4 a, f32x4 b) {
    u32x4 u;
    u[0] = pkbf(a[0], a[1]); u[1] = pkbf(a[2], a[3]);
    u[2] = pkbf(b[0], b[1]); u[3] = pkbf(b[2], b[3]);
    return __builtin_bit_cast(bf16x8, u);
}

// Raw barrier: orders LDS only (lgkmcnt(0) + s_barrier). Global loads/stores
// stay in flight across it.
__device__ __forceinline__ void lds_barrier() {
    asm volatile("s_waitcnt lgkmcnt(0)" ::: "memory");
    __builtin_amdgcn_s_barrier();
}

// Fused diag-block attention, one WG per (batch,block) tile, 512 thr = 8 waves.
// ROUND-5 STRUCTURE: K is never staged in LDS. QK^T reads K fragments
// STRAIGHT from global (NT, depth-4 rolling prefetch interleaved with the
// MFMAs) — load issue is continuous through the compute phase instead of
// bursty, and the serial "stage K -> barrier -> compute" chain is gone
// (first MFMA operands issue at t=0). The 8x intra-WG K re-read is served
// by L2 (~1 MB/WG; HBM sees each byte once). LDS = 32 KB (P only), ONE
// barrier in the whole kernel.
// MEASURED LESSONS (do not re-try):
//  - r2: preloading all 8 Q k-steps (qf[16] fp32) spills past the 128-reg
//    budget (+18 MB scratch writes, +55% time).
//  - r2/r3: removing __builtin_nontemporal_load from streaming Q/K/V loads
//    costs +65 us/dispatch at IDENTICAL traffic (3.67->2.42 TB/s) — keep NT
//    on ALL global loads.
//  - r3: s_setprio around MFMA phases: neutral (barrier-locked phases).
//  - occupancy is register-capped at 2 WG/CU (64 VGPR + 64 AGPR acc2);
//    LDS shrink alone cannot raise it.
__global__ __launch_bounds__(512, 4) void dba_fused(
        const float* __restrict__ Qg, const float* __restrict__ Kg,
        const float* __restrict__ Vg, float* __restrict__ Ag,
        float* __restrict__ Og)
{
    __shared__ unsigned short Sm[BS_ * BS_];  // 32 KB: P[128][128] bf16 (swizzled)

    const int tid  = threadIdx.x;
    const int lane = tid & 63;
    const int w    = tid >> 6;     // wave 0..7
    const int cl   = lane & 15;    // col (C layout) / m (A layout) / n (B layout)
    const int g    = lane >> 4;    // quad group 0..3
    const int bi   = blockIdx.x >> 6;
    const int ni   = blockIdx.x & 63;
    const int base  = (bi * T_ + ni * BS_) * E_;
    const int abase = (bi * T_ + ni * BS_) * BS_;
    const int vcol  = w * 32 + cl;             // this wave's O/V column base

    // Q fragment for ks=0
    const float* qp = Qg + base + (w * 16 + cl) * E_;
    f32x4 q0 = __builtin_nontemporal_load((const f32x4*)(qp + g * 8));
    f32x4 q1 = __builtin_nontemporal_load((const f32x4*)(qp + g * 8 + 4));

    // K fragment base: lane (cl,g) reads K[16*nt+cl][32*ks + 8*g .. +8]
    const float* kp = Kg + base + cl * E_ + g * 8;

    // depth-4 prefetch ring: fragments (ks=0, nt=0..3)
    f32x4 kb[4][2];
    #pragma unroll
    for (int i = 0; i < 4; ++i) {
        kb[i][0] = __builtin_nontemporal_load((const f32x4*)(kp + i * 16 * E_));
        kb[i][1] = __builtin_nontemporal_load((const f32x4*)(kp + i * 16 * E_ + 4));
    }

    // ---- S = Q K^T: K from global, continuous issue, zero LDS, zero barriers ----
    f32x4 acc[8];
    #pragma unroll
    for (int nt = 0; nt < 8; ++nt) acc[nt] = (f32x4){0.f, 0.f, 0.f, 0.f};

    #pragma unroll
    for (int ks = 0; ks < 8; ++ks) {          // contraction: 8 steps of 32
        bf16x8 aq = pack8(q0, q1);
        if (ks < 7) {
            const int kn = (ks + 1) * 32 + g * 8;
            q0 = __builtin_nontemporal_load((const f32x4*)(qp + kn));
            q1 = __builtin_nontemporal_load((const f32x4*)(qp + kn + 4));
        }
        #pragma unroll
        for (int nt = 0; nt < 8; ++nt) {
            const int slot = nt & 3;
            bf16x8 bk = pack8(kb[slot][0], kb[slot][1]);
            const int pn  = nt + 4;            // prefetch 4 fragments ahead
            const int pks = ks + (pn >> 3);
            const int pnt = pn & 7;
            if (pks < 8) {
                kb[slot][0] = __builtin_nontemporal_load(
                    (const f32x4*)(kp + pnt * 16 * E_ + pks * 32));
                kb[slot][1] = __builtin_nontemporal_load(
                    (const f32x4*)(kp + pnt * 16 * E_ + pks * 32 + 4));
            }
            acc[nt] = __builtin_amdgcn_mfma_f32_16x16x32_bf16(aq, bk, acc[nt], 0, 0, 0);
        }
    }

    // ---- prefetch V k-steps 0,1: latency hides under softmax + A-store + P-write ----
    float vb[2][16];
    #pragma unroll
    for (int t = 0; t < 16; ++t)
        vb[0][t] = __builtin_nontemporal_load(
            Vg + base + (g * 8 + (t & 7)) * E_ + vcol + (t >> 3) * 16);
    #pragma unroll
    for (int t = 0; t < 16; ++t)
        vb[1][t] = __builtin_nontemporal_load(
            Vg + base + (32 + g * 8 + (t & 7)) * E_ + vcol + (t >> 3) * 16);

    // ---- mask + softmax. C layout: col = 16*nt + cl, row = 16*w + 4*g + r ----
    const float scale = 0.0625f;               // 1/sqrt(256)
    const float L2E   = 1.4426950408889634f;
    #pragma unroll
    for (int r = 0; r < 4; ++r) {
        const int q = w * 16 + g * 4 + r;      // local query row
        float m = -__builtin_inff();
        #pragma unroll
        for (int nt = 0; nt < 8; ++nt) {
            const int c = nt * 16 + cl;
            float z = acc[nt][r] * scale;
            z = (c > q) ? -__builtin_inff() : z;
            acc[nt][r] = z;
            m = fmaxf(m, z);
        }
        m = fmaxf(m, __shfl_xor(m, 1));
        m = fmaxf(m, __shfl_xor(m, 2));
        m = fmaxf(m, __shfl_xor(m, 4));
        m = fmaxf(m, __shfl_xor(m, 8));
        float s = 0.f;
        #pragma unroll
        for (int nt = 0; nt < 8; ++nt) {
            const float p = exp2f((acc[nt][r] - m) * L2E);
            acc[nt][r] = p;
            s += p;
        }
        s += __shfl_xor(s, 1);
        s += __shfl_xor(s, 2);
        s += __shfl_xor(s, 4);
        s += __shfl_xor(s, 8);
        const float rinv = __builtin_amdgcn_rcpf(s);
        #pragma unroll
        for (int nt = 0; nt < 8; ++nt)
            acc[nt][r] *= rinv;
    }

    // ---- store A (fp32, mandatory output #2). Fire-and-forget. ----
    #pragma unroll
    for (int nt = 0; nt < 8; ++nt)
        #pragma unroll
        for (int r = 0; r < 4; ++r)
            __builtin_nontemporal_store(acc[nt][r],
                Ag + abase + (w * 16 + g * 4 + r) * BS_ + nt * 16 + cl);

    // ---- P (bf16) -> LDS [q][k], 16B-chunk XOR swizzle by (q&15).
    //      Fresh buffer, writes-before-reads only -> no pre-barrier needed. ----
    #pragma unroll
    for (int nt = 0; nt < 8; ++nt)
        #pragma unroll
        for (int r = 0; r < 4; ++r) {
            const int q = w * 16 + g * 4 + r;
            const int k = nt * 16 + cl;
            Sm[q * BS_ + (((k >> 3) ^ (g * 4 + r)) * 8) + (k & 7)] = bf1(acc[nt][r]);
        }

    lds_barrier();   // P visible WG-wide (the only barrier in the kernel)

    // ---- O = P V: wave w owns output cols [32w,32w+32), all 8 q-row tiles.
    //      A-operand from P-LDS (swizzled b128 reads), B-operand = V from
    //      global (each byte read exactly once per WG), depth-2 prefetch. ----
    f32x4 acc2[8][2];
    #pragma unroll
    for (int mt = 0; mt < 8; ++mt) {
        acc2[mt][0] = (f32x4){0.f, 0.f, 0.f, 0.f};
        acc2[mt][1] = (f32x4){0.f, 0.f, 0.f, 0.f};
    }

    #pragma unroll
    for (int ks = 0; ks < 4; ++ks) {
        f32x4 v0a = {vb[ks & 1][0],  vb[ks & 1][1],  vb[ks & 1][2],  vb[ks & 1][3]};
        f32x4 v0b = {vb[ks & 1][4],  vb[ks & 1][5],  vb[ks & 1][6],  vb[ks & 1][7]};
        f32x4 v1a = {vb[ks & 1][8],  vb[ks & 1][9],  vb[ks & 1][10], vb[ks & 1][11]};
        f32x4 v1b = {vb[ks & 1][12], vb[ks & 1][13], vb[ks & 1][14], vb[ks & 1][15]};
        bf16x8 bv0 = pack8(v0a, v0b);
        bf16x8 bv1 = pack8(v1a, v1b);
        if (ks < 2) {   // prefetch k-steps 2,3 into the buffer just consumed
            #pragma unroll
            for (int t = 0; t < 16; ++t)
                vb[ks & 1][t] = __builtin_nontemporal_load(
                    Vg + base + ((ks + 2) * 32 + g * 8 + (t & 7)) * E_ + vcol + (t >> 3) * 16);
        }
        #pragma unroll
        for (int mt = 0; mt < 8; ++mt) {
            const int q = mt * 16 + cl;        // P row; q&15 == cl
            const bf16x8 pa = *(const bf16x8*)&Sm[q * BS_ + (((ks * 4 + g) ^ cl) * 8)];
            acc2[mt][0] = __builtin_amdgcn_mfma_f32_16x16x32_bf16(pa, bv0, acc2[mt][0], 0, 0, 0);
            acc2[mt][1] = __builtin_amdgcn_mfma_f32_16x16x32_bf16(pa, bv1, acc2[mt][1], 0, 0, 0);
        }
    }

    #pragma unroll
    for (int mt = 0; mt < 8; ++mt)
        #pragma unroll
        for (int n2 = 0; n2 < 2; ++n2)
            #pragma unroll
            for (int r = 0; r < 4; ++r)
                __builtin_nontemporal_store(acc2[mt][n2][r],
                    Og + base + (mt * 16 + g * 4 + r) * E_ + vcol + n2 * 16);
}

extern "C" void kernel_launch(void* const* d_in, const int* in_sizes, int n_in,
                              void* d_out, int out_size, void* d_ws, size_t ws_size,
                              hipStream_t stream) {
    const float* Q = (const float*)d_in[0];
    const float* K = (const float*)d_in[1];
    const float* V = (const float*)d_in[2];
    float* O = (float*)d_out;
    const int b = in_sizes[0] / (T_ * E_);            // 16
    float* A = O + (size_t)b * T_ * E_;               // output #2 region of d_out
    dim3 grid(b * (T_ / BS_));                        // 1024 tiles
    dim3 block(512);
    dba_fused<<<grid, block, 0, stream>>>(Q, K, V, A, O);
}

// Round 6
// 469.580 us; speedup vs baseline: 1.2976x; 1.2976x over previous
//
#include <hip/hip_runtime.h>

#define T_  8192
#define E_  256
#define BS_ 128

typedef __attribute__((ext_vector_type(8))) short bf16x8;
typedef __attribute__((ext_vector_type(4))) float f32x4;

__device__ __forceinline__ unsigned short f2bf(float x) {
    unsigned int u = __float_as_uint(x);
    u += 0x7fffu + ((u >> 16) & 1u);           // round-to-nearest-even
    return (unsigned short)(u >> 16);
}

__device__ __forceinline__ bf16x8 pack8(f32x4 a, f32x4 b) {
    bf16x8 r;
    r[0] = (short)f2bf(a[0]); r[1] = (short)f2bf(a[1]);
    r[2] = (short)f2bf(a[2]); r[3] = (short)f2bf(a[3]);
    r[4] = (short)f2bf(b[0]); r[5] = (short)f2bf(b[1]);
    r[6] = (short)f2bf(b[2]); r[7] = (short)f2bf(b[3]);
    return r;
}

// Raw barrier: orders LDS only (lgkmcnt(0) + s_barrier). Global loads/stores
// stay in flight across it.
__device__ __forceinline__ void lds_barrier() {
    asm volatile("s_waitcnt lgkmcnt(0)" ::: "memory");
    __builtin_amdgcn_s_barrier();
}

// Fused diag-block attention. ROUND-6: 1024-thread WG (16 waves) per tile,
// HALF the per-wave register footprint of the 512-thread version so that
// __launch_bounds__(1024,8) fits 2 WGs/CU = 32 waves/CU (2x the TLP of all
// prior rounds, which were latency-bound at Occupancy=37%).
//   QK^T: wave w owns row-tile (w>>1), col-half (w&1) -> acc[4] (16 regs).
//   PV:   wave w owns output cols [16w,16w+16)        -> acc2[8] (32 regs).
//   Softmax rows are split across wave pairs -> cross-wave max/sum combine
//   via 2x512B LDS buffers + 2 extra lgkm-only barriers.
// MEASURED LESSONS (do not re-try):
//  - r2/r3: removing __builtin_nontemporal_load from streaming loads costs
//    +65 us at identical traffic. Keep NT on all single-use global loads.
//  - r5: K-from-global + NT = redundant reads go to HBM (FETCH +257 MB,
//    2.2x time). Intra-WG-reused data MUST be staged in LDS.
//  - r1 vs r4: f2bf bit-math (122 us) beat pkbf casts (130 us); keep f2bf.
//  - r3: s_setprio neutral (barrier-locked phases).
__global__ __launch_bounds__(1024, 8) void dba_fused(
        const float* __restrict__ Qg, const float* __restrict__ Kg,
        const float* __restrict__ Vg, float* __restrict__ Ag,
        float* __restrict__ Og)
{
    __shared__ unsigned short Sm[BS_ * E_];   // 64 KB: K[128][256] bf16 swizzled; later P[128][128] bf16 in low 32 KB
    __shared__ float RedM[2][BS_];            // 512 B: per-col-half partial row max
    __shared__ float RedS[2][BS_];            // 512 B: per-col-half partial row sum

    const int tid  = threadIdx.x;
    const int lane = tid & 63;
    const int w    = tid >> 6;     // wave 0..15
    const int cl   = lane & 15;    // col (C layout) / m (A layout) / n (B layout)
    const int g    = lane >> 4;    // quad group 0..3
    const int rt   = w >> 1;       // row-tile 0..7 (QK^T / softmax)
    const int h    = w & 1;        // col-half 0..1 (QK^T / softmax)
    const int bi   = blockIdx.x >> 6;
    const int ni   = blockIdx.x & 63;
    const int base  = (bi * T_ + ni * BS_) * E_;
    const int abase = (bi * T_ + ni * BS_) * BS_;
    const int vcol  = w * 16 + cl;             // this wave's O/V column

    // Q fragment for ks=0 (pair waves 2rt,2rt+1 read the same rows; 2nd is L2-hit)
    const float* qp = Qg + base + (rt * 16 + cl) * E_;
    f32x4 q0 = __builtin_nontemporal_load((const f32x4*)(qp + g * 8));
    f32x4 q1 = __builtin_nontemporal_load((const f32x4*)(qp + g * 8 + 4));

    // ---- stage K: fp32 global -> bf16 LDS, 16B-chunk XOR swizzle by (row&15) ----
    {
        const int c4   = lane * 4;            // col 0..252 step 4
        const int chnk = c4 >> 3;
        const int klow = c4 & 7;              // 0 or 4
        #pragma unroll
        for (int i = 0; i < 8; ++i) {
            const int n = i * 16 + w;         // key row 0..127
            f32x4 kv = __builtin_nontemporal_load((const f32x4*)(Kg + base + n * E_ + c4));
            const int cp = chnk ^ (n & 15);
            uint2 pk;
            pk.x = (unsigned)f2bf(kv[0]) | ((unsigned)f2bf(kv[1]) << 16);
            pk.y = (unsigned)f2bf(kv[2]) | ((unsigned)f2bf(kv[3]) << 16);
            *(uint2*)&Sm[n * E_ + cp * 8 + klow] = pk;
        }
    }
    lds_barrier();   // bar1: K staged

    // ---- S = Q K^T: wave w -> row-tile rt, col-tiles 4h..4h+3 ----
    f32x4 acc[4];
    #pragma unroll
    for (int j = 0; j < 4; ++j) acc[j] = (f32x4){0.f, 0.f, 0.f, 0.f};

    for (int ks = 0; ks < 8; ++ks) {          // contraction: 8 steps of 32
        bf16x8 aq = pack8(q0, q1);
        if (ks < 7) {
            const int kn = (ks + 1) * 32 + g * 8;
            q0 = __builtin_nontemporal_load((const f32x4*)(qp + kn));
            q1 = __builtin_nontemporal_load((const f32x4*)(qp + kn + 4));
        }
        #pragma unroll
        for (int j = 0; j < 4; ++j) {
            const int n  = (h * 4 + j) * 16 + cl;   // key row
            const int cp = (ks * 4 + g) ^ cl;
            bf16x8 bk = *(const bf16x8*)&Sm[n * E_ + cp * 8];
            acc[j] = __builtin_amdgcn_mfma_f32_16x16x32_bf16(aq, bk, acc[j], 0, 0, 0);
        }
    }

    // ---- prefetch V k-steps 0,1 (16 dwords): latency hides under softmax
    //      (incl. 2 barriers) + A-store + P-write + bar4 ----
    f32x4 vb[2][2];
    #pragma unroll
    for (int t = 0; t < 8; ++t)
        vb[0][t >> 2][t & 3] = __builtin_nontemporal_load(
            Vg + base + (g * 8 + t) * E_ + vcol);
    #pragma unroll
    for (int t = 0; t < 8; ++t)
        vb[1][t >> 2][t & 3] = __builtin_nontemporal_load(
            Vg + base + (32 + g * 8 + t) * E_ + vcol);

    // ---- mask + scale + wave-local row max; publish per-half partials ----
    const float scale = 0.0625f;               // 1/sqrt(256)
    const float L2E   = 1.4426950408889634f;
    #pragma unroll
    for (int r = 0; r < 4; ++r) {
        const int q = rt * 16 + g * 4 + r;     // local query row
        float m = -__builtin_inff();
        #pragma unroll
        for (int j = 0; j < 4; ++j) {
            const int c = (h * 4 + j) * 16 + cl;
            float z = acc[j][r] * scale;
            z = (c > q) ? -__builtin_inff() : z;
            acc[j][r] = z;
            m = fmaxf(m, z);
        }
        m = fmaxf(m, __shfl_xor(m, 1));
        m = fmaxf(m, __shfl_xor(m, 2));
        m = fmaxf(m, __shfl_xor(m, 4));
        m = fmaxf(m, __shfl_xor(m, 8));
        if (cl == 0) RedM[h][q] = m;
    }
    lds_barrier();   // bar2: partial maxes visible (also: all K-LDS reads done)

    // ---- combined max -> exp -> wave-local sum; publish per-half partials ----
    #pragma unroll
    for (int r = 0; r < 4; ++r) {
        const int q = rt * 16 + g * 4 + r;
        const float m = fmaxf(RedM[0][q], RedM[1][q]);
        float s = 0.f;
        #pragma unroll
        for (int j = 0; j < 4; ++j) {
            const float p = exp2f((acc[j][r] - m) * L2E);
            acc[j][r] = p;
            s += p;
        }
        s += __shfl_xor(s, 1);
        s += __shfl_xor(s, 2);
        s += __shfl_xor(s, 4);
        s += __shfl_xor(s, 8);
        if (cl == 0) RedS[h][q] = s;
    }
    lds_barrier();   // bar3: partial sums visible

    // ---- normalize; store A (fp32, mandatory output, fire-and-forget);
    //      write P (bf16) into Sm low 32 KB (K reads finished at bar2) ----
    #pragma unroll
    for (int r = 0; r < 4; ++r) {
        const int q = rt * 16 + g * 4 + r;
        const float rinv = __builtin_amdgcn_rcpf(RedS[0][q] + RedS[1][q]);
        #pragma unroll
        for (int j = 0; j < 4; ++j) {
            const float p = acc[j][r] * rinv;
            acc[j][r] = p;
            const int k = (h * 4 + j) * 16 + cl;
            __builtin_nontemporal_store(p, Ag + abase + q * BS_ + k);
            Sm[q * BS_ + (((k >> 3) ^ (g * 4 + r)) * 8) + (k & 7)] = f2bf(p);
        }
    }
    lds_barrier();   // bar4: P visible WG-wide

    // ---- O = P V: wave w owns output cols [16w,16w+16), all 8 row-tiles.
    //      A-operand from P-LDS (swizzled b128), B-operand = V from global
    //      (each byte read exactly once per WG), depth-2 rolling prefetch. ----
    f32x4 acc2[8];
    #pragma unroll
    for (int mt = 0; mt < 8; ++mt) acc2[mt] = (f32x4){0.f, 0.f, 0.f, 0.f};

    #pragma unroll
    for (int ks = 0; ks < 4; ++ks) {
        bf16x8 bv = pack8(vb[ks & 1][0], vb[ks & 1][1]);
        if (ks < 2) {   // prefetch k-steps 2,3 into the buffer just consumed
            #pragma unroll
            for (int t = 0; t < 8; ++t)
                vb[ks & 1][t >> 2][t & 3] = __builtin_nontemporal_load(
                    Vg + base + ((ks + 2) * 32 + g * 8 + t) * E_ + vcol);
        }
        #pragma unroll
        for (int mt = 0; mt < 8; ++mt) {
            const int q = mt * 16 + cl;        // P row; q&15 == cl
            const bf16x8 pa = *(const bf16x8*)&Sm[q * BS_ + (((ks * 4 + g) ^ cl) * 8)];
            acc2[mt] = __builtin_amdgcn_mfma_f32_16x16x32_bf16(pa, bv, acc2[mt], 0, 0, 0);
        }
    }

    #pragma unroll
    for (int mt = 0; mt < 8; ++mt)
        #pragma unroll
        for (int r = 0; r < 4; ++r)
            __builtin_nontemporal_store(acc2[mt][r],
                Og + base + (mt * 16 + g * 4 + r) * E_ + vcol);
}

extern "C" void kernel_launch(void* const* d_in, const int* in_sizes, int n_in,
                              void* d_out, int out_size, void* d_ws, size_t ws_size,
                              hipStream_t stream) {
    const float* Q = (const float*)d_in[0];
    const float* K = (const float*)d_in[1];
    const float* V = (const float*)d_in[2];
    float* O = (float*)d_out;
    const int b = in_sizes[0] / (T_ * E_);            // 16
    float* A = O + (size_t)b * T_ * E_;               // output #2 region of d_out
    dim3 grid(b * (T_ / BS_));                        // 1024 tiles
    dim3 block(1024);
    dba_fused<<<grid, block, 0, stream>>>(Q, K, V, A, O);
}